// Round 6
// baseline (439.559 us; speedup 1.0000x reference)
//
#include <hip/hip_runtime.h>
#include <hip/hip_bf16.h>
#include <math.h>

#define B_SZ 4
#define T_SZ 2048
#define D_SZ 1024
#define H_SZ 16
#define K_SZ 64

typedef __attribute__((ext_vector_type(8))) short bf8_t;   // 8 bf16 MFMA A/B frag
typedef __attribute__((ext_vector_type(4))) float f4_t;    // 4 fp32 MFMA C/D frag

// exp2-folded softmax scale: (1/sqrt(64)) * log2(e)
#define QSCALE 0.18033688011112042f

__device__ __forceinline__ ushort f2bf(float f) {          // RNE float->bf16
    union { float f; unsigned u; } v; v.f = f;
    return (ushort)((v.u + 0x7fffu + ((v.u >> 16) & 1u)) >> 16);
}

__device__ __forceinline__ uint pack2bf(float a, float b) { // packed RNE pair
    union { __hip_bfloat162 h; uint u; } v;
    v.h = __float22bfloat162_rn(make_float2(a, b));
    return v.u;
}

__device__ __forceinline__ void gld_lds16(const ushort* g, ushort* l) {
    __builtin_amdgcn_global_load_lds(
        (const __attribute__((address_space(1))) void*)g,
        (__attribute__((address_space(3))) void*)l, 16, 0, 0);
}

// ---------------------------------------------------------------------------
// Prep 1: elementwise fp32 -> bf16
// ---------------------------------------------------------------------------
__global__ __launch_bounds__(256) void convert_bf16_kernel(
    const float* __restrict__ src, ushort* __restrict__ dst)
{
    const size_t i = ((size_t)blockIdx.x * 256 + threadIdx.x) * 8;
    float4 a = *(const float4*)(src + i);
    float4 b = *(const float4*)(src + i + 4);
    ushort o[8] = {f2bf(a.x), f2bf(a.y), f2bf(a.z), f2bf(a.w),
                   f2bf(b.x), f2bf(b.y), f2bf(b.z), f2bf(b.w)};
    *(uint4*)(dst + i) = *(const uint4*)o;
}

// ---------------------------------------------------------------------------
// Prep 2: Wq/Wk/Wv (H,D,K) fp32 -> WT (3072 x 1024) bf16
// ---------------------------------------------------------------------------
__global__ __launch_bounds__(256) void transpose_w_kernel(
    const float* __restrict__ Wq, const float* __restrict__ Wk,
    const float* __restrict__ Wv, ushort* __restrict__ WT)
{
    __shared__ __align__(16) float tile[64][68];
    const int tid = threadIdx.x;
    const int d0  = blockIdx.x * 64;
    const int g   = blockIdx.y;
    const int sel = g >> 4, h = g & 15;
    const float* W = (sel == 0 ? Wq : (sel == 1 ? Wk : Wv)) + (size_t)h * D_SZ * K_SZ;

    {
        const int r = tid >> 2, ks = (tid & 3) * 16;
        const float4* src = (const float4*)(W + (size_t)(d0 + r) * 64 + ks);
        float4* dst = (float4*)&tile[r][ks];
        dst[0] = src[0]; dst[1] = src[1]; dst[2] = src[2]; dst[3] = src[3];
    }
    __syncthreads();
    {
        const int k = tid >> 2, ds = (tid & 3) * 16;
        ushort o[16];
        #pragma unroll
        for (int i = 0; i < 16; ++i) o[i] = f2bf(tile[ds + i][k]);
        uint4* dst = (uint4*)&WT[(size_t)(sel * 1024 + h * 64 + k) * 1024 + d0 + ds];
        dst[0] = ((const uint4*)o)[0];
        dst[1] = ((const uint4*)o)[1];
    }
}

// ---------------------------------------------------------------------------
// Shared MFMA gemm_bt core (m97 structure)
// ---------------------------------------------------------------------------
__device__ __forceinline__ void gemm_bt_tile(
    const ushort* __restrict__ A, const ushort* __restrict__ Bt,
    int Kdim, int m0, int n0, ushort* As, ushort* Bs, f4_t acc[4][4])
{
    const int tid  = threadIdx.x;
    const int lane = tid & 63, wv = tid >> 6;
    const int l16  = lane & 15, quad = lane >> 4;
    const int wm   = (wv >> 1) * 64, wn = (wv & 1) * 64;
    const int sw   = (l16 >> 1) & 3;

    const int ra0 = tid >> 2,         qa0 = (tid & 3) ^ ((ra0 >> 1) & 3);
    const int ra1 = (tid + 256) >> 2, qa1 = (tid & 3) ^ ((ra1 >> 1) & 3);
    ushort* ldsA0 = As + (size_t)(wv * 64) * 8;
    ushort* ldsA1 = As + (size_t)(wv * 64 + 256) * 8;
    ushort* ldsB0 = Bs + (size_t)(wv * 64) * 8;
    ushort* ldsB1 = Bs + (size_t)(wv * 64 + 256) * 8;
    const ushort* gA0 = A  + (size_t)(m0 + ra0) * Kdim + qa0 * 8;
    const ushort* gA1 = A  + (size_t)(m0 + ra1) * Kdim + qa1 * 8;
    const ushort* gB0 = Bt + (size_t)(n0 + ra0) * Kdim + qa0 * 8;
    const ushort* gB1 = Bt + (size_t)(n0 + ra1) * Kdim + qa1 * 8;

    for (int k0 = 0; k0 < Kdim; k0 += 32) {
        __syncthreads();
        gld_lds16(gA0 + k0, ldsA0);
        gld_lds16(gA1 + k0, ldsA1);
        gld_lds16(gB0 + k0, ldsB0);
        gld_lds16(gB1 + k0, ldsB1);
        __syncthreads();

        bf8_t a[4], b[4];
        #pragma unroll
        for (int mt = 0; mt < 4; ++mt)
            a[mt] = *(const bf8_t*)&As[(wm + mt * 16 + l16) * 32 + ((quad ^ sw) * 8)];
        #pragma unroll
        for (int nt = 0; nt < 4; ++nt)
            b[nt] = *(const bf8_t*)&Bs[(wn + nt * 16 + l16) * 32 + ((quad ^ sw) * 8)];
        #pragma unroll
        for (int mt = 0; mt < 4; ++mt)
            #pragma unroll
            for (int nt = 0; nt < 4; ++nt)
                acc[mt][nt] = __builtin_amdgcn_mfma_f32_16x16x32_bf16(
                    a[mt], b[nt], acc[mt][nt], 0, 0, 0);
    }
}

// ---------------------------------------------------------------------------
// QKV projection GEMM. Q pre-scaled by QSCALE (exp2-folded softmax scale).
// V blocks (sel==2) write Vt (B,H,K,T) DIRECTLY via b64 stores (transpose
// fused into epilogue; lane's 4 r-values are consecutive t).
// ---------------------------------------------------------------------------
__global__ __launch_bounds__(256) void gemm_qkv_kernel(
    const ushort* __restrict__ Xb, const ushort* __restrict__ WT,
    ushort* __restrict__ Qo, ushort* __restrict__ Ko, ushort* __restrict__ Vt)
{
    __shared__ __align__(16) ushort As[128 * 32];
    __shared__ __align__(16) ushort Bs[128 * 32];
    const int n0 = blockIdx.x * 128, m0 = blockIdx.y * 128;

    f4_t acc[4][4];
    #pragma unroll
    for (int i = 0; i < 4; ++i)
        #pragma unroll
        for (int j = 0; j < 4; ++j) acc[i][j] = (f4_t){0.f, 0.f, 0.f, 0.f};

    gemm_bt_tile(Xb, WT, 1024, m0, n0, As, Bs, acc);

    const int tid = threadIdx.x;
    const int lane = tid & 63, wv = tid >> 6;
    const int l16 = lane & 15, quad = lane >> 4;
    const int wm = (wv >> 1) * 64, wn = (wv & 1) * 64;
    const int sel = n0 >> 10;

    if (sel < 2) {
        ushort* Out = (sel == 0) ? Qo : Ko;
        const float osc = (sel == 0) ? QSCALE : 1.0f;
        #pragma unroll
        for (int nt = 0; nt < 4; ++nt) {
            const int col = n0 + wn + nt * 16 + l16;
            const int h = (col >> 6) & 15, kk = col & 63;
            #pragma unroll
            for (int mt = 0; mt < 4; ++mt) {
                const int row0 = m0 + wm + mt * 16 + quad * 4;
                const int bb = row0 >> 11, t = row0 & 2047;
                uint u01 = pack2bf(acc[mt][nt][0] * osc, acc[mt][nt][1] * osc);
                uint u23 = pack2bf(acc[mt][nt][2] * osc, acc[mt][nt][3] * osc);
                ushort* dst = &Out[((size_t)(bb * 16 + h) * 2048 + t) * 64 + kk];
                dst[0]       = (ushort)u01;
                dst[64]      = (ushort)(u01 >> 16);
                dst[128]     = (ushort)u23;
                dst[192]     = (ushort)(u23 >> 16);
            }
        }
    } else {
        // Vt[(bb*16+h)*64 + kk][t..t+3] <- acc rows (consecutive t)
        #pragma unroll
        for (int nt = 0; nt < 4; ++nt) {
            const int col = n0 + wn + nt * 16 + l16;
            const int h = (col >> 6) & 15, kk = col & 63;
            #pragma unroll
            for (int mt = 0; mt < 4; ++mt) {
                const int row0 = m0 + wm + mt * 16 + quad * 4;
                const int bb = row0 >> 11, t = row0 & 2047;
                uint2 pk;
                pk.x = pack2bf(acc[mt][nt][0], acc[mt][nt][1]);
                pk.y = pack2bf(acc[mt][nt][2], acc[mt][nt][3]);
                *(uint2*)&Vt[((size_t)((bb * 16 + h) * 64 + kk)) * 2048 + t] = pk;
            }
        }
    }
}

// ---------------------------------------------------------------------------
// Output projection GEMM (unchanged)
// ---------------------------------------------------------------------------
__global__ __launch_bounds__(256) void gemm_out_kernel(
    const ushort* __restrict__ Yb, const ushort* __restrict__ WoB,
    const float* __restrict__ bo, float* __restrict__ Out)
{
    __shared__ __align__(16) ushort As[128 * 32];
    __shared__ __align__(16) ushort Bs[128 * 32];
    const int n0 = blockIdx.x * 128, m0 = blockIdx.y * 128;

    f4_t acc[4][4];
    #pragma unroll
    for (int i = 0; i < 4; ++i)
        #pragma unroll
        for (int j = 0; j < 4; ++j) acc[i][j] = (f4_t){0.f, 0.f, 0.f, 0.f};

    gemm_bt_tile(Yb, WoB, 1024, m0, n0, As, Bs, acc);

    const int tid = threadIdx.x;
    const int lane = tid & 63, wv = tid >> 6;
    const int l16 = lane & 15, quad = lane >> 4;
    const int wm = (wv >> 1) * 64, wn = (wv & 1) * 64;

    #pragma unroll
    for (int nt = 0; nt < 4; ++nt) {
        const int col = n0 + wn + nt * 16 + l16;
        const float bias = bo[col];
        #pragma unroll
        for (int mt = 0; mt < 4; ++mt) {
            #pragma unroll
            for (int r = 0; r < 4; ++r) {
                const int row = m0 + wm + mt * 16 + quad * 4 + r;
                Out[(size_t)row * 1024 + col] = acc[mt][nt][r] + bias;
            }
        }
    }
}

// ---------------------------------------------------------------------------
// MFMA flash attention v4.
// 512 threads = 8 waves; q-tile 256 (wave owns 32 rows); grid (8,64), LPT.
// Fixed-base softmax (exp2, scale folded into Q; mask-after-exp select-to-0).
// Double-buffered K/Vt staging: exactly 1 K + 1 V gld_lds chunk per lane per
// iteration; one barrier per iteration. LDS 68 KB -> 2 blocks/CU (16 waves).
// ---------------------------------------------------------------------------
__global__ __launch_bounds__(512, 4) void attn_mfma_kernel(
    const ushort* __restrict__ Qg, const ushort* __restrict__ Kg,
    const ushort* __restrict__ Vtg, ushort* __restrict__ Y)
{
    __shared__ __align__(16) ushort Ks[2][64 * 64];
    __shared__ __align__(16) ushort Vs[2][64 * 64];
    __shared__ __align__(16) ushort Pl[8][32 * 72];

    const int tid  = threadIdx.x;
    const int w    = tid >> 6;             // 0..7
    const int lane = tid & 63;
    const int l16  = lane & 15;
    const int quad = lane >> 4;
    const int qi = 7 - blockIdx.x;         // LPT order
    const int bh = blockIdx.y;
    const int bb = bh >> 4, h = bh & 15;

    const int Q0   = qi * 256;
    const int trow = Q0 + w * 32;

    bf8_t qa[2][2];
    #pragma unroll
    for (int mt = 0; mt < 2; ++mt) {
        const ushort* qp = Qg + ((size_t)bh * T_SZ + trow + mt * 16 + l16) * K_SZ + quad * 8;
        qa[mt][0] = *(const bf8_t*)qp;
        qa[mt][1] = *(const bf8_t*)(qp + 32);
    }

    f4_t O[2][4];
    #pragma unroll
    for (int mt = 0; mt < 2; ++mt)
        #pragma unroll
        for (int dt = 0; dt < 4; ++dt) O[mt][dt] = (f4_t){0.f, 0.f, 0.f, 0.f};
    float lp[2][4];
    #pragma unroll
    for (int mt = 0; mt < 2; ++mt)
        #pragma unroll
        for (int r = 0; r < 4; ++r) lp[mt][r] = 0.f;

    ushort* myP = Pl[w];
    const int sw_r = ((l16 >> 2) & 3) << 4;
    const int g_ln  = (lane & 7) ^ (lane >> 3);   // swizzled global chunk
    const int srow  = w * 8 + (lane >> 3);        // staging row 0..63

    const ushort* Kbh = Kg  + (size_t)bh * T_SZ * K_SZ;
    const ushort* Vbh = Vtg + (size_t)bh * K_SZ * T_SZ;

    const int n_it = 4 * qi + 4;

    // preload tile 0 into buffer 0 (1 K-chunk + 1 V-chunk per lane)
    gld_lds16(Kbh + (size_t)srow * K_SZ + g_ln * 8, &Ks[0][w * 512]);
    gld_lds16(Vbh + (size_t)srow * T_SZ + g_ln * 8, &Vs[0][w * 512]);

    int cur = 0;
    for (int it = 0; it < n_it; ++it) {
        const int s0 = it * 64;

        __syncthreads();                   // buf[cur] ready; prev frag reads done
        if (it + 1 < n_it) {
            const int sn = s0 + 64, nb = cur ^ 1;
            gld_lds16(Kbh + (size_t)(sn + srow) * K_SZ + g_ln * 8, &Ks[nb][w * 512]);
            gld_lds16(Vbh + (size_t)srow * T_SZ + sn + g_ln * 8,  &Vs[nb][w * 512]);
        }

        if (s0 < trow + 32) {              // wave-uniform: useful work exists
            const ushort* Kc = Ks[cur];
            const ushort* Vc = Vs[cur];

            bf8_t kb[4][2], vb[4][2];
            #pragma unroll
            for (int nt = 0; nt < 4; ++nt) {
                const int sr = nt * 16 + l16;
                kb[nt][0] = *(const bf8_t*)&Kc[sr * 64 + ((quad ^ (sr & 7)) * 8)];
                kb[nt][1] = *(const bf8_t*)&Kc[sr * 64 + (((quad + 4) ^ (sr & 7)) * 8)];
                vb[nt][0] = *(const bf8_t*)&Vc[sr * 64 + ((quad ^ (sr & 7)) * 8)];
                vb[nt][1] = *(const bf8_t*)&Vc[sr * 64 + (((quad + 4) ^ (sr & 7)) * 8)];
            }

            // S = Q K^T
            f4_t S[2][4];
            #pragma unroll
            for (int mt = 0; mt < 2; ++mt)
                #pragma unroll
                for (int nt = 0; nt < 4; ++nt) S[mt][nt] = (f4_t){0.f, 0.f, 0.f, 0.f};
            #pragma unroll
            for (int mt = 0; mt < 2; ++mt)
                #pragma unroll
                for (int nt = 0; nt < 4; ++nt) {
                    S[mt][nt] = __builtin_amdgcn_mfma_f32_16x16x32_bf16(
                        qa[mt][0], kb[nt][0], S[mt][nt], 0, 0, 0);
                    S[mt][nt] = __builtin_amdgcn_mfma_f32_16x16x32_bf16(
                        qa[mt][1], kb[nt][1], S[mt][nt], 0, 0, 0);
                }

            const bool diag = (s0 + 64 > trow);

            // p = exp2(S) (scale pre-folded); causal mask via select-to-0
            #pragma unroll
            for (int mt = 0; mt < 2; ++mt) {
                float p[4][4];
                #pragma unroll
                for (int nt = 0; nt < 4; ++nt) {
                    const int sg = s0 + nt * 16 + l16;
                    #pragma unroll
                    for (int r = 0; r < 4; ++r) {
                        float pv = exp2f(S[mt][nt][r]);
                        if (diag && sg > trow + mt * 16 + quad * 4 + r) pv = 0.f;
                        p[nt][r] = pv;
                        lp[mt][r] += pv;
                    }
                }
                #pragma unroll
                for (int nt = 0; nt < 4; ++nt) {
                    const int colp = (nt * 16 + l16) ^ (quad << 4);
                    uint u01 = pack2bf(p[nt][0], p[nt][1]);
                    uint u23 = pack2bf(p[nt][2], p[nt][3]);
                    ushort* pw = &myP[(mt * 16 + quad * 4) * 72 + colp];
                    pw[0]       = (ushort)u01;
                    pw[72]      = (ushort)(u01 >> 16);
                    pw[144]     = (ushort)u23;
                    pw[216]     = (ushort)(u23 >> 16);
                }
            }
            asm volatile("" ::: "memory");
            bf8_t pa[2][2];
            #pragma unroll
            for (int mt = 0; mt < 2; ++mt) {
                const ushort* pr = &myP[(mt * 16 + l16) * 72];
                pa[mt][0] = *(const bf8_t*)(pr + ((quad * 8) ^ sw_r));
                pa[mt][1] = *(const bf8_t*)(pr + ((32 + quad * 8) ^ sw_r));
            }

            // O += P V
            #pragma unroll
            for (int dt = 0; dt < 4; ++dt)
                #pragma unroll
                for (int mt = 0; mt < 2; ++mt) {
                    O[mt][dt] = __builtin_amdgcn_mfma_f32_16x16x32_bf16(
                        pa[mt][0], vb[dt][0], O[mt][dt], 0, 0, 0);
                    O[mt][dt] = __builtin_amdgcn_mfma_f32_16x16x32_bf16(
                        pa[mt][1], vb[dt][1], O[mt][dt], 0, 0, 0);
                }
        }
        cur ^= 1;
    }

    // epilogue: one shuffle reduction of l per row, then normalize + store
    #pragma unroll
    for (int mt = 0; mt < 2; ++mt) {
        float inv[4];
        #pragma unroll
        for (int r = 0; r < 4; ++r) {
            float s = lp[mt][r];
            #pragma unroll
            for (int off = 1; off < 16; off <<= 1)
                s += __shfl_xor(s, off);
            inv[r] = 1.f / s;
        }
        #pragma unroll
        for (int dt = 0; dt < 4; ++dt) {
            const int col = h * 64 + dt * 16 + l16;
            #pragma unroll
            for (int r = 0; r < 4; ++r) {
                const int tg = trow + mt * 16 + quad * 4 + r;
                Y[((size_t)(bb * T_SZ + tg)) * (H_SZ * K_SZ) + col] =
                    f2bf(O[mt][dt][r] * inv[r]);
            }
        }
    }
}

extern "C" void kernel_launch(void* const* d_in, const int* in_sizes, int n_in,
                              void* d_out, int out_size, void* d_ws, size_t ws_size,
                              hipStream_t stream) {
    const float* X  = (const float*)d_in[0];
    const float* Wq = (const float*)d_in[1];
    const float* Wk = (const float*)d_in[2];
    const float* Wv = (const float*)d_in[3];
    const float* Wo = (const float*)d_in[4];
    const float* bo = (const float*)d_in[5];
    float* out = (float*)d_out;

    const size_t NE = (size_t)B_SZ * H_SZ * T_SZ * K_SZ;   // 8388608
    ushort* Qb   = (ushort*)d_ws;
    ushort* Kb   = Qb + NE;
    ushort* Vtb  = Kb + NE;
    ushort* Yb   = Vtb + NE;
    ushort* Xb   = Yb + NE;
    ushort* WT   = Xb + NE;
    ushort* WoB  = WT + (size_t)3072 * 1024;

    convert_bf16_kernel<<<dim3(4096), 256, 0, stream>>>(X, Xb);
    convert_bf16_kernel<<<dim3(512), 256, 0, stream>>>(Wo, WoB);
    transpose_w_kernel<<<dim3(16, 48), 256, 0, stream>>>(Wq, Wk, Wv, WT);
    gemm_qkv_kernel<<<dim3(24, 64), 256, 0, stream>>>(Xb, WT, Qb, Kb, Vtb);
    attn_mfma_kernel<<<dim3(8, 64), 512, 0, stream>>>(Qb, Kb, Vtb, Yb);
    gemm_out_kernel<<<dim3(8, 64), 256, 0, stream>>>(Yb, WoB, bo, out);
}

// Round 7
// 352.650 us; speedup vs baseline: 1.2464x; 1.2464x over previous
//
#include <hip/hip_runtime.h>
#include <hip/hip_bf16.h>
#include <math.h>

#define B_SZ 4
#define T_SZ 2048
#define D_SZ 1024
#define H_SZ 16
#define K_SZ 64

typedef __attribute__((ext_vector_type(8))) short bf8_t;   // 8 bf16 MFMA A/B frag
typedef __attribute__((ext_vector_type(4))) short bf4_t;   // 4 bf16 (16x16x16 frag)
typedef __attribute__((ext_vector_type(4))) float f4_t;    // 4 fp32 MFMA C/D frag

// exp2-folded softmax scale: (1/sqrt(64)) * log2(e)
#define QSCALE 0.18033688011112042f

__device__ __forceinline__ ushort f2bf(float f) {          // RNE float->bf16
    union { float f; unsigned u; } v; v.f = f;
    return (ushort)((v.u + 0x7fffu + ((v.u >> 16) & 1u)) >> 16);
}

__device__ __forceinline__ uint pack2bf(float a, float b) { // packed RNE pair
    union { __hip_bfloat162 h; uint u; } v;
    v.h = __float22bfloat162_rn(make_float2(a, b));
    return v.u;
}

__device__ __forceinline__ bf4_t pack4bf(float a, float b, float c, float d) {
    union { uint2 u; bf4_t s; } v;
    v.u.x = pack2bf(a, b);
    v.u.y = pack2bf(c, d);
    return v.s;
}

__device__ __forceinline__ void gld_lds16(const ushort* g, ushort* l) {
    __builtin_amdgcn_global_load_lds(
        (const __attribute__((address_space(1))) void*)g,
        (__attribute__((address_space(3))) void*)l, 16, 0, 0);
}

// ---------------------------------------------------------------------------
// Prep 1: elementwise fp32 -> bf16
// ---------------------------------------------------------------------------
__global__ __launch_bounds__(256) void convert_bf16_kernel(
    const float* __restrict__ src, ushort* __restrict__ dst)
{
    const size_t i = ((size_t)blockIdx.x * 256 + threadIdx.x) * 8;
    float4 a = *(const float4*)(src + i);
    float4 b = *(const float4*)(src + i + 4);
    ushort o[8] = {f2bf(a.x), f2bf(a.y), f2bf(a.z), f2bf(a.w),
                   f2bf(b.x), f2bf(b.y), f2bf(b.z), f2bf(b.w)};
    *(uint4*)(dst + i) = *(const uint4*)o;
}

// ---------------------------------------------------------------------------
// Prep 2: Wq/Wk/Wv (H,D,K) fp32 -> WT (3072 x 1024) bf16
// ---------------------------------------------------------------------------
__global__ __launch_bounds__(256) void transpose_w_kernel(
    const float* __restrict__ Wq, const float* __restrict__ Wk,
    const float* __restrict__ Wv, ushort* __restrict__ WT)
{
    __shared__ __align__(16) float tile[64][68];
    const int tid = threadIdx.x;
    const int d0  = blockIdx.x * 64;
    const int g   = blockIdx.y;
    const int sel = g >> 4, h = g & 15;
    const float* W = (sel == 0 ? Wq : (sel == 1 ? Wk : Wv)) + (size_t)h * D_SZ * K_SZ;

    {
        const int r = tid >> 2, ks = (tid & 3) * 16;
        const float4* src = (const float4*)(W + (size_t)(d0 + r) * 64 + ks);
        float4* dst = (float4*)&tile[r][ks];
        dst[0] = src[0]; dst[1] = src[1]; dst[2] = src[2]; dst[3] = src[3];
    }
    __syncthreads();
    {
        const int k = tid >> 2, ds = (tid & 3) * 16;
        ushort o[16];
        #pragma unroll
        for (int i = 0; i < 16; ++i) o[i] = f2bf(tile[ds + i][k]);
        uint4* dst = (uint4*)&WT[(size_t)(sel * 1024 + h * 64 + k) * 1024 + d0 + ds];
        dst[0] = ((const uint4*)o)[0];
        dst[1] = ((const uint4*)o)[1];
    }
}

// ---------------------------------------------------------------------------
// Shared MFMA gemm_bt core (m97 structure)
// ---------------------------------------------------------------------------
__device__ __forceinline__ void gemm_bt_tile(
    const ushort* __restrict__ A, const ushort* __restrict__ Bt,
    int Kdim, int m0, int n0, ushort* As, ushort* Bs, f4_t acc[4][4])
{
    const int tid  = threadIdx.x;
    const int lane = tid & 63, wv = tid >> 6;
    const int l16  = lane & 15, quad = lane >> 4;
    const int wm   = (wv >> 1) * 64, wn = (wv & 1) * 64;
    const int sw   = (l16 >> 1) & 3;

    const int ra0 = tid >> 2,         qa0 = (tid & 3) ^ ((ra0 >> 1) & 3);
    const int ra1 = (tid + 256) >> 2, qa1 = (tid & 3) ^ ((ra1 >> 1) & 3);
    ushort* ldsA0 = As + (size_t)(wv * 64) * 8;
    ushort* ldsA1 = As + (size_t)(wv * 64 + 256) * 8;
    ushort* ldsB0 = Bs + (size_t)(wv * 64) * 8;
    ushort* ldsB1 = Bs + (size_t)(wv * 64 + 256) * 8;
    const ushort* gA0 = A  + (size_t)(m0 + ra0) * Kdim + qa0 * 8;
    const ushort* gA1 = A  + (size_t)(m0 + ra1) * Kdim + qa1 * 8;
    const ushort* gB0 = Bt + (size_t)(n0 + ra0) * Kdim + qa0 * 8;
    const ushort* gB1 = Bt + (size_t)(n0 + ra1) * Kdim + qa1 * 8;

    for (int k0 = 0; k0 < Kdim; k0 += 32) {
        __syncthreads();
        gld_lds16(gA0 + k0, ldsA0);
        gld_lds16(gA1 + k0, ldsA1);
        gld_lds16(gB0 + k0, ldsB0);
        gld_lds16(gB1 + k0, ldsB1);
        __syncthreads();

        bf8_t a[4], b[4];
        #pragma unroll
        for (int mt = 0; mt < 4; ++mt)
            a[mt] = *(const bf8_t*)&As[(wm + mt * 16 + l16) * 32 + ((quad ^ sw) * 8)];
        #pragma unroll
        for (int nt = 0; nt < 4; ++nt)
            b[nt] = *(const bf8_t*)&Bs[(wn + nt * 16 + l16) * 32 + ((quad ^ sw) * 8)];
        #pragma unroll
        for (int mt = 0; mt < 4; ++mt)
            #pragma unroll
            for (int nt = 0; nt < 4; ++nt)
                acc[mt][nt] = __builtin_amdgcn_mfma_f32_16x16x32_bf16(
                    a[mt], b[nt], acc[mt][nt], 0, 0, 0);
    }
}

// ---------------------------------------------------------------------------
// QKV projection GEMM. Q pre-scaled by QSCALE (exp2-folded softmax scale).
// V blocks (sel==2) write Vt (B,H,K,T) directly (transpose fused).
// ---------------------------------------------------------------------------
__global__ __launch_bounds__(256) void gemm_qkv_kernel(
    const ushort* __restrict__ Xb, const ushort* __restrict__ WT,
    ushort* __restrict__ Qo, ushort* __restrict__ Ko, ushort* __restrict__ Vt)
{
    __shared__ __align__(16) ushort As[128 * 32];
    __shared__ __align__(16) ushort Bs[128 * 32];
    const int n0 = blockIdx.x * 128, m0 = blockIdx.y * 128;

    f4_t acc[4][4];
    #pragma unroll
    for (int i = 0; i < 4; ++i)
        #pragma unroll
        for (int j = 0; j < 4; ++j) acc[i][j] = (f4_t){0.f, 0.f, 0.f, 0.f};

    gemm_bt_tile(Xb, WT, 1024, m0, n0, As, Bs, acc);

    const int tid = threadIdx.x;
    const int lane = tid & 63, wv = tid >> 6;
    const int l16 = lane & 15, quad = lane >> 4;
    const int wm = (wv >> 1) * 64, wn = (wv & 1) * 64;
    const int sel = n0 >> 10;

    if (sel < 2) {
        ushort* Out = (sel == 0) ? Qo : Ko;
        const float osc = (sel == 0) ? QSCALE : 1.0f;
        #pragma unroll
        for (int nt = 0; nt < 4; ++nt) {
            const int col = n0 + wn + nt * 16 + l16;
            const int h = (col >> 6) & 15, kk = col & 63;
            #pragma unroll
            for (int mt = 0; mt < 4; ++mt) {
                const int row0 = m0 + wm + mt * 16 + quad * 4;
                const int bb = row0 >> 11, t = row0 & 2047;
                uint u01 = pack2bf(acc[mt][nt][0] * osc, acc[mt][nt][1] * osc);
                uint u23 = pack2bf(acc[mt][nt][2] * osc, acc[mt][nt][3] * osc);
                ushort* dst = &Out[((size_t)(bb * 16 + h) * 2048 + t) * 64 + kk];
                dst[0]   = (ushort)u01;
                dst[64]  = (ushort)(u01 >> 16);
                dst[128] = (ushort)u23;
                dst[192] = (ushort)(u23 >> 16);
            }
        }
    } else {
        #pragma unroll
        for (int nt = 0; nt < 4; ++nt) {
            const int col = n0 + wn + nt * 16 + l16;
            const int h = (col >> 6) & 15, kk = col & 63;
            #pragma unroll
            for (int mt = 0; mt < 4; ++mt) {
                const int row0 = m0 + wm + mt * 16 + quad * 4;
                const int bb = row0 >> 11, t = row0 & 2047;
                uint2 pk;
                pk.x = pack2bf(acc[mt][nt][0], acc[mt][nt][1]);
                pk.y = pack2bf(acc[mt][nt][2], acc[mt][nt][3]);
                *(uint2*)&Vt[((size_t)((bb * 16 + h) * 64 + kk)) * 2048 + t] = pk;
            }
        }
    }
}

// ---------------------------------------------------------------------------
// Output projection GEMM (unchanged)
// ---------------------------------------------------------------------------
__global__ __launch_bounds__(256) void gemm_out_kernel(
    const ushort* __restrict__ Yb, const ushort* __restrict__ WoB,
    const float* __restrict__ bo, float* __restrict__ Out)
{
    __shared__ __align__(16) ushort As[128 * 32];
    __shared__ __align__(16) ushort Bs[128 * 32];
    const int n0 = blockIdx.x * 128, m0 = blockIdx.y * 128;

    f4_t acc[4][4];
    #pragma unroll
    for (int i = 0; i < 4; ++i)
        #pragma unroll
        for (int j = 0; j < 4; ++j) acc[i][j] = (f4_t){0.f, 0.f, 0.f, 0.f};

    gemm_bt_tile(Yb, WoB, 1024, m0, n0, As, Bs, acc);

    const int tid = threadIdx.x;
    const int lane = tid & 63, wv = tid >> 6;
    const int l16 = lane & 15, quad = lane >> 4;
    const int wm = (wv >> 1) * 64, wn = (wv & 1) * 64;

    #pragma unroll
    for (int nt = 0; nt < 4; ++nt) {
        const int col = n0 + wn + nt * 16 + l16;
        const float bias = bo[col];
        #pragma unroll
        for (int mt = 0; mt < 4; ++mt) {
            #pragma unroll
            for (int r = 0; r < 4; ++r) {
                const int row = m0 + wm + mt * 16 + quad * 4 + r;
                Out[(size_t)row * 1024 + col] = acc[mt][nt][r] + bias;
            }
        }
    }
}

// ---------------------------------------------------------------------------
// MFMA flash attention v5 (transpose-trick, no P LDS round-trip).
// 256 thr = 4 waves, q-tile 128 (wave owns 32 rows), grid (16,64), LPT.
// S^T = K Q^T via 16x16x32 (operands swapped): P^T lands in C-layout =
// exactly the A-frag layout of 16x16x16 MFMA -> PV chains from registers.
// Fixed-base softmax (exp2, scale folded into Q), per-lane l partials
// (per-q already, since C-cols = q), 2 cross-quad shuffles in epilogue.
// Double-buffered K/Vt staging via gld_lds, one barrier/iter. LDS 32 KB.
// ---------------------------------------------------------------------------
__global__ __launch_bounds__(256) void attn_mfma_kernel(
    const ushort* __restrict__ Qg, const ushort* __restrict__ Kg,
    const ushort* __restrict__ Vtg, ushort* __restrict__ Y)
{
    __shared__ __align__(16) ushort Ks[2][64 * 64];
    __shared__ __align__(16) ushort Vs[2][64 * 64];

    const int tid  = threadIdx.x;
    const int w    = tid >> 6;
    const int lane = tid & 63;
    const int l16  = lane & 15;
    const int quad = lane >> 4;
    const int qi = 15 - blockIdx.x;        // LPT order
    const int bh = blockIdx.y;
    const int bb = bh >> 4, h = bh & 15;

    const int Q0   = qi * 128;
    const int trow = Q0 + w * 32;

    // Q frags (B-operand of S^T: B[k=d][n=q] = Q[q][d], same data layout)
    bf8_t qa[2][2];
    #pragma unroll
    for (int qt = 0; qt < 2; ++qt) {
        const ushort* qp = Qg + ((size_t)bh * T_SZ + trow + qt * 16 + l16) * K_SZ + quad * 8;
        qa[qt][0] = *(const bf8_t*)qp;
        qa[qt][1] = *(const bf8_t*)(qp + 32);
    }

    f4_t O[2][4];                          // [qt][dt]; lane: q=quad*4+r, d=dt*16+l16
    #pragma unroll
    for (int qt = 0; qt < 2; ++qt)
        #pragma unroll
        for (int dt = 0; dt < 4; ++dt) O[qt][dt] = (f4_t){0.f, 0.f, 0.f, 0.f};
    float lp[2] = {0.f, 0.f};              // per-lane l partial for q = l16

    const int g_ln  = (lane & 7) ^ (lane >> 3);
    const int rr_ln = lane >> 3;

    const ushort* Kbh = Kg  + (size_t)bh * T_SZ * K_SZ;
    const ushort* Vbh = Vtg + (size_t)bh * K_SZ * T_SZ;

    const int n_it = 2 * qi + 2;

    // preload tile 0 into buffer 0
    #pragma unroll
    for (int j = 0; j < 2; ++j) {
        const int r8 = (j * 4 + w) * 8 + rr_ln;
        gld_lds16(Kbh + (size_t)r8 * K_SZ + g_ln * 8, &Ks[0][(j * 4 + w) * 512]);
        gld_lds16(Vbh + (size_t)r8 * T_SZ + g_ln * 8, &Vs[0][(j * 4 + w) * 512]);
    }

    int cur = 0;
    for (int it = 0; it < n_it; ++it) {
        const int s0 = it * 64;

        __syncthreads();                   // buf[cur] ready; prev frag reads done
        if (it + 1 < n_it) {
            const int sn = s0 + 64, nb = cur ^ 1;
            #pragma unroll
            for (int j = 0; j < 2; ++j) {
                const int r8 = (j * 4 + w) * 8 + rr_ln;
                gld_lds16(Kbh + (size_t)(sn + r8) * K_SZ + g_ln * 8,
                          &Ks[nb][(j * 4 + w) * 512]);
                gld_lds16(Vbh + (size_t)r8 * T_SZ + sn + g_ln * 8,
                          &Vs[nb][(j * 4 + w) * 512]);
            }
        }

        if (s0 < trow + 32) {              // wave-uniform: useful work exists
            const ushort* Kc = Ks[cur];
            const ushort* Vc = Vs[cur];

            // K frags (A-operand of S^T: A[m=s][k=d], same addresses as before)
            bf8_t ka[4][2];
            #pragma unroll
            for (int st = 0; st < 4; ++st) {
                const int sr = st * 16 + l16;
                ka[st][0] = *(const bf8_t*)&Kc[sr * 64 + ((quad ^ (sr & 7)) * 8)];
                ka[st][1] = *(const bf8_t*)&Kc[sr * 64 + (((quad + 4) ^ (sr & 7)) * 8)];
            }

            // S^T = K Q^T: C-tile (st,qt): lane holds S^T[s=quad*4+r][q=l16]
            f4_t St[4][2];
            #pragma unroll
            for (int st = 0; st < 4; ++st)
                #pragma unroll
                for (int qt = 0; qt < 2; ++qt) St[st][qt] = (f4_t){0.f, 0.f, 0.f, 0.f};
            #pragma unroll
            for (int st = 0; st < 4; ++st)
                #pragma unroll
                for (int qt = 0; qt < 2; ++qt) {
                    St[st][qt] = __builtin_amdgcn_mfma_f32_16x16x32_bf16(
                        ka[st][0], qa[qt][0], St[st][qt], 0, 0, 0);
                    St[st][qt] = __builtin_amdgcn_mfma_f32_16x16x32_bf16(
                        ka[st][1], qa[qt][1], St[st][qt], 0, 0, 0);
                }

            const bool diag = (s0 + 64 > trow);

            // p = exp2(S^T) (+causal select-to-0); P^T C-layout == 16x16x16
            // A-frag layout -> pack directly to bf16 A-frags
            bf4_t pa[4][2];
            #pragma unroll
            for (int st = 0; st < 4; ++st) {
                const int sgb = s0 + st * 16 + quad * 4;
                #pragma unroll
                for (int qt = 0; qt < 2; ++qt) {
                    const int qg = trow + qt * 16 + l16;
                    float p[4];
                    #pragma unroll
                    for (int r = 0; r < 4; ++r) {
                        float pv = exp2f(St[st][qt][r]);
                        if (diag && (sgb + r) > qg) pv = 0.f;
                        p[r] = pv;
                    }
                    lp[qt] += p[0] + p[1] + p[2] + p[3];
                    pa[st][qt] = pack4bf(p[0], p[1], p[2], p[3]);
                }
            }

            // O += P V via 16x16x16 MFMA; V B-frag = 4 consecutive s (8B LDS)
            #pragma unroll
            for (int st = 0; st < 4; ++st) {
                const int chl = st * 2 + (quad >> 1);  // global chunk of s-range
                const int off = (quad & 1) * 4;
                #pragma unroll
                for (int dt = 0; dt < 4; ++dt) {
                    const int dr = dt * 16 + l16;
                    bf4_t vb = *(const bf4_t*)&Vc[dr * 64 + ((chl ^ (dr & 7)) * 8) + off];
                    #pragma unroll
                    for (int qt = 0; qt < 2; ++qt)
                        O[qt][dt] = __builtin_amdgcn_mfma_f32_16x16x16bf16_1k(
                            pa[st][qt], vb, O[qt][dt], 0, 0, 0);
                }
            }
        }
        cur ^= 1;
    }

    // epilogue: reduce l across quads (per q=l16), fetch inv per O-row, store
    #pragma unroll
    for (int qt = 0; qt < 2; ++qt) {
        float s = lp[qt];
        s += __shfl_xor(s, 16);
        s += __shfl_xor(s, 32);
        const float inv = 1.f / s;         // valid at lanes where l16 == q_local
        float invr[4];
        #pragma unroll
        for (int r = 0; r < 4; ++r)
            invr[r] = __shfl(inv, quad * 4 + r);   // src lane l16 = quad*4+r
        #pragma unroll
        for (int dt = 0; dt < 4; ++dt) {
            const int col = h * 64 + dt * 16 + l16;
            #pragma unroll
            for (int r = 0; r < 4; ++r) {
                const int tg = trow + qt * 16 + quad * 4 + r;
                Y[((size_t)(bb * T_SZ + tg)) * (H_SZ * K_SZ) + col] =
                    f2bf(O[qt][dt][r] * invr[r]);
            }
        }
    }
}

extern "C" void kernel_launch(void* const* d_in, const int* in_sizes, int n_in,
                              void* d_out, int out_size, void* d_ws, size_t ws_size,
                              hipStream_t stream) {
    const float* X  = (const float*)d_in[0];
    const float* Wq = (const float*)d_in[1];
    const float* Wk = (const float*)d_in[2];
    const float* Wv = (const float*)d_in[3];
    const float* Wo = (const float*)d_in[4];
    const float* bo = (const float*)d_in[5];
    float* out = (float*)d_out;

    const size_t NE = (size_t)B_SZ * H_SZ * T_SZ * K_SZ;   // 8388608
    ushort* Qb   = (ushort*)d_ws;
    ushort* Kb   = Qb + NE;
    ushort* Vtb  = Kb + NE;
    ushort* Yb   = Vtb + NE;
    ushort* Xb   = Yb + NE;
    ushort* WT   = Xb + NE;
    ushort* WoB  = WT + (size_t)3072 * 1024;

    convert_bf16_kernel<<<dim3(4096), 256, 0, stream>>>(X, Xb);
    convert_bf16_kernel<<<dim3(512), 256, 0, stream>>>(Wo, WoB);
    transpose_w_kernel<<<dim3(16, 48), 256, 0, stream>>>(Wq, Wk, Wv, WT);
    gemm_qkv_kernel<<<dim3(24, 64), 256, 0, stream>>>(Xb, WT, Qb, Kb, Vtb);
    attn_mfma_kernel<<<dim3(16, 64), 256, 0, stream>>>(Qb, Kb, Vtb, Yb);
    gemm_out_kernel<<<dim3(8, 64), 256, 0, stream>>>(Yb, WoB, bo, out);
}